// Round 5
// baseline (31.398 us; speedup 1.0000x reference)
//
#include <hip/hip_runtime.h>

#define CONF_THR 2.5f
#define NCLS 80
#define BLOCK 256
#define ROWS_PER_STEP 64              // per block per step (4 waves x 16 rows)
#define STEPS_PER_BLOCK 2
#define ROWS_PER_BLOCK (ROWS_PER_STEP * STEPS_PER_BLOCK)   // 128

// Fully-coalesced pass1: each wave streams 5 contiguous 1KB float4 chunks
// (= 16 rows of 80 floats), per-float4 maxes -> wave-private LDS, then 32
// lanes re-read 20 maxes each for per-row maxes. No __syncthreads until the
// final block reduction. Boxes loaded as contiguous 64-float bursts.
__global__ __launch_bounds__(BLOCK, 8) void yolo_pass1(
    const float* __restrict__ post,
    const float* __restrict__ boxes,
    float* __restrict__ partial, int n) {

    const int tid  = threadIdx.x;
    const int lane = tid & 63;
    const int wav  = tid >> 6;
    const long nfloat4 = (long)n * (NCLS / 4);   // 6,000,000 float4s of post

    // steps handled by this block: s0, s0+1 (step = 64 rows of the matrix)
    const int s0 = blockIdx.x * STEPS_PER_BLOCK;

    __shared__ float smax[4][STEPS_PER_BLOCK][320];   // per-wave max scratch
    __shared__ float wsum[4];

    const float4* post4 = reinterpret_cast<const float4*>(post);
    const float4 ninf = make_float4(-1e30f, -1e30f, -1e30f, -1e30f);

    // ---- load phase: 10 coalesced float4 + 2 coalesced box floats ----
    float4 v[STEPS_PER_BLOCK][5];
    float  bx[STEPS_PER_BLOCK];
    #pragma unroll
    for (int s = 0; s < STEPS_PER_BLOCK; ++s) {
        // float4-stream base for (step, wave): 1280 f4 per step, 320 per wave
        const long F = (long)(s0 + s) * 1280 + wav * 320;
        #pragma unroll
        for (int i = 0; i < 5; ++i) {
            const long idx = F + i * 64 + lane;       // contiguous per instr
            v[s][i] = (idx < nfloat4) ? post4[idx] : ninf;
        }
        // rows covered by this wave this step: rbase .. rbase+15
        const int rbase = (s0 + s) * ROWS_PER_STEP + wav * 16;
        const int brow  = rbase + (lane >> 2);        // lane l -> row, coord l&3
        bx[s] = (brow < n) ? boxes[(size_t)rbase * 4 + lane] : 0.0f;
    }

    // ---- per-float4 maxes -> wave-private LDS (no barrier needed) ----
    #pragma unroll
    for (int s = 0; s < STEPS_PER_BLOCK; ++s) {
        #pragma unroll
        for (int i = 0; i < 5; ++i) {
            float m = fmaxf(fmaxf(v[s][i].x, v[s][i].y),
                            fmaxf(v[s][i].z, v[s][i].w));
            smax[wav][s][i * 64 + lane] = m;
        }
    }

    // ---- row maxes: 32 lanes, each reduces 20 contiguous LDS floats ----
    float rowmax = -1e30f;
    {
        const int s = (lane >> 4) & 1;   // lanes 0-15 -> step 0, 16-31 -> step 1
        const int r = lane & 15;
        if (lane < 32) {
            const float4* p = reinterpret_cast<const float4*>(&smax[wav][s][r * 20]);
            float4 a0 = p[0], a1 = p[1], a2 = p[2], a3 = p[3], a4 = p[4];
            float m0 = fmaxf(fmaxf(a0.x, a0.y), fmaxf(a0.z, a0.w));
            float m1 = fmaxf(fmaxf(a1.x, a1.y), fmaxf(a1.z, a1.w));
            float m2 = fmaxf(fmaxf(a2.x, a2.y), fmaxf(a2.z, a2.w));
            float m3 = fmaxf(fmaxf(a3.x, a3.y), fmaxf(a3.z, a3.w));
            float m4 = fmaxf(fmaxf(a4.x, a4.y), fmaxf(a4.z, a4.w));
            rowmax = fmaxf(fmaxf(fmaxf(m0, m1), fmaxf(m2, m3)), m4);
        }
    }

    // ---- broadcast row maxes to box-holding lanes; accumulate ----
    const float m0 = __shfl(rowmax, lane >> 2);         // step 0: lanes 0..15
    const float m1 = __shfl(rowmax, 16 + (lane >> 2));  // step 1: lanes 16..31
    float c = 0.0f;
    if (m0 >= CONF_THR) c += bx[0] + (((lane & 3) == 0) ? m0 : 0.0f);
    if (m1 >= CONF_THR) c += bx[1] + (((lane & 3) == 0) ? m1 : 0.0f);

    // ---- 64-lane butterfly, block reduce, one partial per block ----
    #pragma unroll
    for (int off = 1; off < 64; off <<= 1)
        c += __shfl_xor(c, off);

    if (lane == 0) wsum[wav] = c;
    __syncthreads();
    if (tid == 0) partial[blockIdx.x] = wsum[0] + wsum[1] + wsum[2] + wsum[3];
}

// Pass 2: reduce nb per-block partials -> scalar. Plain store, deterministic.
__global__ __launch_bounds__(1024) void yolo_pass2(
    const float* __restrict__ partial, float* __restrict__ out, int nb) {

    const int tid  = threadIdx.x;
    const int lane = tid & 63;
    const int wav  = tid >> 6;

    float s = 0.0f;
    for (int i = tid; i < nb; i += 1024) s += partial[i];

    #pragma unroll
    for (int off = 1; off < 64; off <<= 1)
        s += __shfl_xor(s, off);

    __shared__ float ws[16];
    if (lane == 0) ws[wav] = s;
    __syncthreads();
    if (tid == 0) {
        float t = 0.0f;
        #pragma unroll
        for (int w = 0; w < 16; ++w) t += ws[w];
        out[0] = t;
    }
}

extern "C" void kernel_launch(void* const* d_in, const int* in_sizes, int n_in,
                              void* d_out, int out_size, void* d_ws, size_t ws_size,
                              hipStream_t stream) {
    const float* post  = (const float*)d_in[0];   // [N, 80] f32
    const float* boxes = (const float*)d_in[1];   // [N, 4]  f32
    float* out     = (float*)d_out;               // scalar f32
    float* partial = (float*)d_ws;                // nb floats of scratch

    const int n  = in_sizes[0] / NCLS;            // 300000
    const int nb = (n + ROWS_PER_BLOCK - 1) / ROWS_PER_BLOCK;   // 2344

    yolo_pass1<<<nb, BLOCK, 0, stream>>>(post, boxes, partial, n);
    yolo_pass2<<<1, 1024, 0, stream>>>(partial, out, nb);
}

// Round 6
// 21.957 us; speedup vs baseline: 1.4300x; 1.4300x over previous
//
#include <hip/hip_runtime.h>

#define CONF_THR 2.5f
#define NCLS 80
#define BLOCK 256
#define ITERS 5
#define ROWS_PER_BLOCK (64 * ITERS)   // 320 rows per block -> grid 938

// R3 structure (best so far), ITERS pushed to 5 to raise in-flight loads:
// 4 lanes per row, 5 rows per thread. Pure load phase (30 loads in flight,
// ~100 dest VGPRs), then compute. __launch_bounds__(256,4) pins VGPR<=128
// so 4 waves/SIMD stay resident: 4 x 30 = 120 loads/SIMD in flight (+25%
// over the saturated-at-96 R3/R4 configs).
__global__ __launch_bounds__(BLOCK, 4) void yolo_pass1(
    const float* __restrict__ post,
    const float* __restrict__ boxes,
    float* __restrict__ partial, int n) {

    const int tid  = threadIdx.x;
    const int lane = tid & 63;
    const int wav  = tid >> 6;
    const int q    = tid & 3;       // quarter-row / box-coord index
    const int sub  = tid >> 2;      // row-in-group 0..63
    const int base = blockIdx.x * ROWS_PER_BLOCK;

    float4 v[ITERS][5];
    float  bx[ITERS];

    // ---- load phase: all independent, all in flight ----
    #pragma unroll
    for (int it = 0; it < ITERS; ++it) {
        const int row = base + it * 64 + sub;
        if (row < n) {
            const float4* p = reinterpret_cast<const float4*>(
                post + (size_t)row * NCLS + q * 20);
            bx[it] = boxes[(size_t)row * 4 + q];
            v[it][0] = p[0]; v[it][1] = p[1]; v[it][2] = p[2];
            v[it][3] = p[3]; v[it][4] = p[4];
        } else {
            const float4 ninf = make_float4(-1e30f, -1e30f, -1e30f, -1e30f);
            v[it][0] = ninf; v[it][1] = ninf; v[it][2] = ninf;
            v[it][3] = ninf; v[it][4] = ninf;
            bx[it] = 0.0f;
        }
    }

    // ---- compute phase ----
    float c = 0.0f;
    #pragma unroll
    for (int it = 0; it < ITERS; ++it) {
        float m0 = fmaxf(fmaxf(v[it][0].x, v[it][0].y), fmaxf(v[it][0].z, v[it][0].w));
        float m1 = fmaxf(fmaxf(v[it][1].x, v[it][1].y), fmaxf(v[it][1].z, v[it][1].w));
        float m2 = fmaxf(fmaxf(v[it][2].x, v[it][2].y), fmaxf(v[it][2].z, v[it][2].w));
        float m3 = fmaxf(fmaxf(v[it][3].x, v[it][3].y), fmaxf(v[it][3].z, v[it][3].w));
        float m4 = fmaxf(fmaxf(v[it][4].x, v[it][4].y), fmaxf(v[it][4].z, v[it][4].w));
        float m  = fmaxf(fmaxf(fmaxf(m0, m1), fmaxf(m2, m3)), m4);
        // max across the 4-lane group sharing this row
        m = fmaxf(m, __shfl_xor(m, 1));
        m = fmaxf(m, __shfl_xor(m, 2));
        if (m >= CONF_THR) c += bx[it] + ((q == 0) ? m : 0.0f);
    }

    // ---- 64-lane butterfly sum, block reduce, one partial per block ----
    #pragma unroll
    for (int off = 1; off < 64; off <<= 1)
        c += __shfl_xor(c, off);

    __shared__ float ws[4];
    if (lane == 0) ws[wav] = c;
    __syncthreads();
    if (tid == 0) partial[blockIdx.x] = ws[0] + ws[1] + ws[2] + ws[3];
}

// Pass 2: reduce nb per-block partials -> scalar. Plain store, deterministic.
__global__ __launch_bounds__(1024) void yolo_pass2(
    const float* __restrict__ partial, float* __restrict__ out, int nb) {

    const int tid  = threadIdx.x;
    const int lane = tid & 63;
    const int wav  = tid >> 6;

    float s = 0.0f;
    for (int i = tid; i < nb; i += 1024) s += partial[i];

    #pragma unroll
    for (int off = 1; off < 64; off <<= 1)
        s += __shfl_xor(s, off);

    __shared__ float ws[16];
    if (lane == 0) ws[wav] = s;
    __syncthreads();
    if (tid == 0) {
        float t = 0.0f;
        #pragma unroll
        for (int w = 0; w < 16; ++w) t += ws[w];
        out[0] = t;
    }
}

extern "C" void kernel_launch(void* const* d_in, const int* in_sizes, int n_in,
                              void* d_out, int out_size, void* d_ws, size_t ws_size,
                              hipStream_t stream) {
    const float* post  = (const float*)d_in[0];   // [N, 80] f32
    const float* boxes = (const float*)d_in[1];   // [N, 4]  f32
    float* out     = (float*)d_out;               // scalar f32
    float* partial = (float*)d_ws;                // nb floats of scratch

    const int n  = in_sizes[0] / NCLS;            // 300000
    const int nb = (n + ROWS_PER_BLOCK - 1) / ROWS_PER_BLOCK;   // 938

    yolo_pass1<<<nb, BLOCK, 0, stream>>>(post, boxes, partial, n);
    yolo_pass2<<<1, 1024, 0, stream>>>(partial, out, nb);
}